// Round 10
// baseline (882.521 us; speedup 1.0000x reference)
//
#include <hip/hip_runtime.h>
#include <cstdint>
#include <cstddef>

#define XLD 161   // x row stride = NFEAT + EXTRA + 1

typedef float f4u __attribute__((ext_vector_type(4), aligned(4)));  // unaligned-tolerant
typedef float f4a __attribute__((ext_vector_type(4)));              // 16B-aligned
typedef float f3u __attribute__((ext_vector_type(3), aligned(4)));
typedef float f2a __attribute__((ext_vector_type(2)));              // 8B-aligned

// ============================ CSR build ============================
__global__ void hist_kernel(const int* __restrict__ row, int* __restrict__ cnt, int E) {
    for (int e = blockIdx.x * blockDim.x + threadIdx.x; e < E; e += gridDim.x * blockDim.x)
        atomicAdd(&cnt[row[e]], 1);
}

__global__ __launch_bounds__(256)
void scan1_kernel(const int* __restrict__ cnt, int* __restrict__ offs,
                  int* __restrict__ bsums, int n) {
    int t = threadIdx.x;
    int gid = blockIdx.x * 256 + t;
    int v = (gid < n) ? cnt[gid] : 0;
    int x = v;
#pragma unroll
    for (int o = 1; o < 64; o <<= 1) { int y = __shfl_up(x, o); if ((t & 63) >= o) x += y; }
    __shared__ int ws[4];
    if ((t & 63) == 63) ws[t >> 6] = x;
    __syncthreads();
    int add = 0;
    for (int w = 0; w < (t >> 6); w++) add += ws[w];
    int incl = x + add;
    if (gid < n) offs[gid] = incl - v;
    if (t == 255) bsums[blockIdx.x] = incl;
}

__global__ __launch_bounds__(256)
void scan2_kernel(int* __restrict__ bsums, int nb) {
    int t = threadIdx.x;
    int v = (t < nb) ? bsums[t] : 0;
    int x = v;
#pragma unroll
    for (int o = 1; o < 64; o <<= 1) { int y = __shfl_up(x, o); if ((t & 63) >= o) x += y; }
    __shared__ int ws[4];
    if ((t & 63) == 63) ws[t >> 6] = x;
    __syncthreads();
    int add = 0;
    for (int w = 0; w < (t >> 6); w++) add += ws[w];
    if (t < nb) bsums[t] = x + add - v;
}

__global__ void scan3_kernel(int* __restrict__ offs, int* __restrict__ cursor,
                             const int* __restrict__ bsums, int n, int E) {
    int gid = blockIdx.x * 256 + threadIdx.x;
    if (gid < n) {
        int o = offs[gid] + bsums[blockIdx.x];
        offs[gid] = o;
        cursor[gid] = o;
    }
    if (gid == 0) offs[n] = E;
}

__global__ void scatter_kernel(const int* __restrict__ row, const int* __restrict__ col,
                               const float* __restrict__ val, int* __restrict__ cursor,
                               int2* __restrict__ edges, int E) {
    for (int e = blockIdx.x * blockDim.x + threadIdx.x; e < E; e += gridDim.x * blockDim.x) {
        int r = row[e];
        int p = atomicAdd(&cursor[r], 1);
        int2 ed;
        ed.x = col[e];
        ed.y = __float_as_int(val[e]);
        edges[p] = ed;
    }
}

// ============================ helpers ============================
template <int CT>
__device__ inline void ldw(const float* p, float* wv) {
    if constexpr (CT == 2) { *(f2a*)wv = *(const f2a*)p; }
    else if constexpr (CT == 3) { *(f3u*)wv = *(const f3u*)p; }
    else { *(f4a*)wv = *(const f4a*)p; }
}

// ============================ Column-split tiled GEMM ============================
// Out[:, col0:col0+COLS] = A[n x K] @ W[:, col0:col0+COLS] (+cb const row, +bias, relu opt).
// grid = (rowTiles, C/COLS). 256 threads: tc=t&15 owns CT=COLS/16 cols, tr=t>>4 owns 4 rows.
// A element k from A1 (ld1) if k < split else A2 (ld2) at k-split.
template <int K, int COLS, bool HASB, bool RELU, bool HASCB>
__global__ __launch_bounds__(256)
void gemmC(const float* __restrict__ A1, int ld1, int split,
           const float* __restrict__ A2, int ld2,
           const float* __restrict__ W, int ldW,
           const float* __restrict__ bias, const float* __restrict__ cbv,
           float* __restrict__ Out, int ldO, int n) {
    constexpr int CT = COLS / 16;        // 2, 3, or 4
    __shared__ float Wc[16 * COLS];
    __shared__ float At[16][68];

    int t  = threadIdx.x;
    int tc = t & 15, tr = t >> 4;
    int row0 = blockIdx.x * 64;
    int col0 = blockIdx.y * COLS;

    int srow = t >> 2;
    int gr = row0 + srow; if (gr >= n) gr = n - 1;
    int kh = (t & 3) * 4;

    float acc[4][CT];
#pragma unroll
    for (int i = 0; i < 4; i++)
#pragma unroll
        for (int c = 0; c < CT; c++) acc[i][c] = 0.f;

#pragma unroll 1
    for (int kb = 0; kb < K; kb += 16) {
        __syncthreads();
        // stage W chunk (f4 loads; j stays 4-aligned)
        for (int i4 = t * 4; i4 < 16 * COLS; i4 += 1024) {
            int k = i4 / COLS, j = i4 - k * COLS;
            *(f4a*)&Wc[i4] = *(const f4u*)&W[(size_t)(kb + k) * ldW + col0 + j];
        }
        // stage A chunk (transposed)
        {
            int kg = kb + kh;
            const float* src = (kg < split) ? (A1 + (size_t)gr * ld1 + kg)
                                            : (A2 + (size_t)gr * ld2 + (kg - split));
            f4u v = *(const f4u*)src;
#pragma unroll
            for (int e = 0; e < 4; e++) At[kh + e][srow] = v[e];
        }
        __syncthreads();
#pragma unroll
        for (int kk = 0; kk < 16; kk++) {
            f4a av = *(const f4a*)&At[kk][tr * 4];
            float wv[CT];
            ldw<CT>(&Wc[kk * COLS + tc * CT], wv);
#pragma unroll
            for (int i = 0; i < 4; i++)
#pragma unroll
                for (int c = 0; c < CT; c++) acc[i][c] = fmaf(av[i], wv[c], acc[i][c]);
        }
    }

    float bb[CT], cc[CT];
#pragma unroll
    for (int c = 0; c < CT; c++) {
        bb[c] = HASB ? bias[col0 + tc * CT + c] : 0.f;
        cc[c] = HASCB ? cbv[col0 + tc * CT + c] : 0.f;
    }

#pragma unroll
    for (int i = 0; i < 4; i++) {
        int r = row0 + tr * 4 + i;
        if (r < n) {
            float* o = Out + (size_t)r * ldO + col0 + tc * CT;
#pragma unroll
            for (int c = 0; c < CT; c++) {
                float v = acc[i][c] + cc[c] + bb[c];
                if (RELU) v = fmaxf(v, 0.f);
                o[c] = v;
            }
        }
    }
}

// ============================ Aggregation with epilogue ============================
// H[node] = relu( sum_e val*S[col_e] + bias ), optional BN stats.
// 32-lane group per node, 8 groups/block, grid-stride. 32-edge chunks: coalesced int2
// edge load, shfl broadcast, independent full-row gathers (lane owns LC contiguous floats).
template <int LC, bool DOBN>
__global__ __launch_bounds__(256)
void aggE(const float* __restrict__ S, const int* __restrict__ offs,
          const int2* __restrict__ edges, const float* __restrict__ bias,
          float* __restrict__ Hout, float* __restrict__ bsum,
          float* __restrict__ bsumsq, int n) {
    constexpr int C = 32 * LC;
    int lane = threadIdx.x & 63;
    int lg   = lane & 31;
    int grp  = threadIdx.x >> 5;
    int sh   = lane & 32;

    float bir[LC];
#pragma unroll
    for (int a = 0; a < LC; a++) bir[a] = bias[LC * lg + a];

    float psum[LC], psq[LC];
#pragma unroll
    for (int a = 0; a < LC; a++) { psum[a] = 0.f; psq[a] = 0.f; }

    for (int node = blockIdx.x * 8 + grp; node < n; node += gridDim.x * 8) {
        int e0 = offs[node], e1 = offs[node + 1];
        float acc[LC];
#pragma unroll
        for (int a = 0; a < LC; a++) acc[a] = 0.f;

        for (int e = e0; e < e1; e += 32) {
            int  idx = e + lg;
            int2 ed  = (idx < e1) ? edges[idx] : make_int2(0, 0);
            int  cnt = min(32, e1 - e);
#pragma unroll 8
            for (int j = 0; j < cnt; j++) {
                int   c = __shfl(ed.x, sh + j);
                float v = __int_as_float(__shfl(ed.y, sh + j));
                const float* srow = S + (size_t)c * C + LC * lg;
                if (LC == 3) {
                    f3u g = *(const f3u*)srow;
                    acc[0] = fmaf(v, g[0], acc[0]);
                    acc[1] = fmaf(v, g[1], acc[1]);
                    acc[2] = fmaf(v, g[2], acc[2]);
                } else {
                    f2a g = *(const f2a*)srow;
                    acc[0] = fmaf(v, g[0], acc[0]);
                    acc[1] = fmaf(v, g[1], acc[1]);
                }
            }
        }

        float* orow = Hout + (size_t)node * C + LC * lg;
        if (LC == 3) {
            f3u o;
#pragma unroll
            for (int a = 0; a < 3; a++) {
                float tv = fmaxf(acc[a] + bir[a], 0.f);
                o[a] = tv;
                if (DOBN) { psum[a] += tv; psq[a] += tv * tv; }
            }
            *(f3u*)orow = o;
        } else {
            f2a o;
#pragma unroll
            for (int a = 0; a < 2; a++) {
                float tv = fmaxf(acc[a] + bir[a], 0.f);
                o[a] = tv;
                if (DOBN) { psum[a] += tv; psq[a] += tv * tv; }
            }
            *(f2a*)orow = o;
        }
    }

    if (DOBN) {
        __shared__ float red[DOBN ? 8 * C : 1];
#pragma unroll
        for (int a = 0; a < LC; a++) red[grp * C + LC * lg + a] = psum[a];
        __syncthreads();
        if (threadIdx.x < C) {
            float s = 0.f;
            for (int g = 0; g < 8; g++) s += red[g * C + threadIdx.x];
            atomicAdd(&bsum[threadIdx.x], s);
        }
        __syncthreads();
#pragma unroll
        for (int a = 0; a < LC; a++) red[grp * C + LC * lg + a] = psq[a];
        __syncthreads();
        if (threadIdx.x < C) {
            float s = 0.f;
            for (int g = 0; g < 8; g++) s += red[g * C + threadIdx.x];
            atomicAdd(&bsumsq[threadIdx.x], s);
        }
    }
}

// ============================ BN fold: Wf = inv*W, cb = -sum(mean*inv*W) ============================
template <int C>
__global__ __launch_bounds__(256)
void fold_kernel(const float* __restrict__ W, float* __restrict__ bsum,
                 float* __restrict__ bsumsq, float* __restrict__ Wf,
                 float* __restrict__ cb, int N) {
    __shared__ float mean[96], inv[96];
    int t = threadIdx.x;
    float rn = 1.0f / (float)N;
    if (t < 96) {
        float mu  = bsum[t] * rn;
        float var = bsumsq[t] * rn - mu * mu;
        mean[t] = mu;
        inv[t]  = rsqrtf(var + 1e-5f);
        bsum[t] = 0.f;
        bsumsq[t] = 0.f;
    }
    __syncthreads();
    for (int i = t; i < 96 * C; i += 256) {
        int k = i / C;
        Wf[i] = inv[k] * W[i];
    }
    if (t < C) {
        float s = 0.f;
        for (int k = 0; k < 96; k++) s += mean[k] * inv[k] * W[k * C + t];
        cb[t] = -s;
    }
}

// ============================ final dot (64->1) + global min ============================
__global__ __launch_bounds__(256)
void dot_min_kernel(const float* __restrict__ A, const float* __restrict__ M3w,
                    const float* __restrict__ M3b, float* __restrict__ m,
                    unsigned* __restrict__ gmin, int n) {
    int lane = threadIdx.x & 63;
    int wv   = threadIdx.x >> 6;
    float w  = M3w[lane];
    float b  = M3b[0];
    float lmin = 3.4e38f;
    int nw = gridDim.x * 4;
    for (int r = blockIdx.x * 4 + wv; r < n; r += nw) {
        float v = A[(size_t)r * 64 + lane] * w;
#pragma unroll
        for (int o = 32; o; o >>= 1) v += __shfl_down(v, o);
        if (lane == 0) {
            float mv = v + b;
            m[r] = mv;
            lmin = fminf(lmin, mv);
        }
    }
#pragma unroll
    for (int o = 32; o; o >>= 1) lmin = fminf(lmin, __shfl_down(lmin, o));
    __shared__ float sm[4];
    if (lane == 0) sm[wv] = lmin;
    __syncthreads();
    if (threadIdx.x == 0) {
        float mn = fminf(fminf(sm[0], sm[1]), fminf(sm[2], sm[3]));
        unsigned u = __float_as_uint(mn);
        unsigned key = (u >> 31) ? ~u : (u | 0x80000000u);
        atomicMin(gmin, key);
    }
}

__global__ void where_kernel(const float* __restrict__ x, float* __restrict__ m,
                             const unsigned* __restrict__ gmin, int n) {
    int i = blockIdx.x * blockDim.x + threadIdx.x;
    if (i < n) {
        unsigned k = *gmin;
        unsigned u = (k >> 31) ? (k ^ 0x80000000u) : ~k;
        float g = __uint_as_float(u);
        if (x[(size_t)i * XLD + 160] == 0.0f) m[i] = g;
    }
}

// ============================ exact radix select ============================
__device__ inline unsigned fkey(float f) {
    unsigned u = __float_as_uint(f);
    return (u >> 31) ? ~u : (u | 0x80000000u);
}

__global__ __launch_bounds__(1024)
void select_kernel(const float* __restrict__ m, int n, int kwant, float* __restrict__ thresh) {
    __shared__ unsigned hist[256];
    __shared__ unsigned sprefix;
    __shared__ int skk;
    int t = threadIdx.x;
    if (t == 0) { sprefix = 0u; skk = kwant; }
    for (int pass = 0; pass < 4; ++pass) {
        if (t < 256) hist[t] = 0u;
        __syncthreads();
        int shift = 24 - 8 * pass;
        unsigned pfx = sprefix;
        for (int i = t; i < n; i += 1024) {
            unsigned key = fkey(m[i]);
            bool ok = (pass == 0) || ((key >> (shift + 8)) == (pfx >> (shift + 8)));
            if (ok) atomicAdd(&hist[(key >> shift) & 255u], 1u);
        }
        __syncthreads();
        if (t == 0) {
            int cum = 0, kk = skk, chosen = 0;
            for (int b = 255; b >= 0; b--) {
                cum += (int)hist[b];
                if (cum >= kk) { chosen = b; kk -= (cum - (int)hist[b]); break; }
            }
            sprefix = pfx | ((unsigned)chosen << shift);
            skk = kk;
        }
        __syncthreads();
    }
    if (t == 0) {
        unsigned key = sprefix;
        unsigned u = (key >> 31) ? (key ^ 0x80000000u) : ~key;
        *thresh = __uint_as_float(u);
    }
}

__global__ void mask_kernel(const float* __restrict__ m, const float* __restrict__ thresh,
                            float* __restrict__ out, int n) {
    int i = blockIdx.x * blockDim.x + threadIdx.x;
    if (i < n) {
        float t = *thresh, v = m[i];
        out[i] = (v > t) ? v * (1.0f / v) : 0.0f;
    }
}

// ============================ launch ============================
extern "C" void kernel_launch(void* const* d_in, const int* in_sizes, int n_in,
                              void* d_out, int out_size, void* d_ws, size_t ws_size,
                              hipStream_t stream) {
    const float* x   = (const float*)d_in[0];
    const int*   row = (const int*)d_in[1];
    const int*   col = (const int*)d_in[2];
    const float* val = (const float*)d_in[3];
    const float* W1  = (const float*)d_in[4];
    const float* b1  = (const float*)d_in[5];
    const float* W2  = (const float*)d_in[6];
    const float* b2  = (const float*)d_in[7];
    const float* W3  = (const float*)d_in[8];
    const float* b3  = (const float*)d_in[9];
    const float* W4  = (const float*)d_in[10];
    const float* b4  = (const float*)d_in[11];
    const float* W5  = (const float*)d_in[12];
    const float* b5  = (const float*)d_in[13];
    const float* M1w = (const float*)d_in[14];
    const float* M1b = (const float*)d_in[15];
    const float* M2w = (const float*)d_in[16];
    const float* M2b = (const float*)d_in[17];
    const float* M3w = (const float*)d_in[18];
    const float* M3b = (const float*)d_in[19];

    const int n = in_sizes[0] / XLD;   // 50000
    const int E = in_sizes[1];         // 800000

    char* ws = (char*)d_ws;
    size_t off = 0;
    auto carve = [&](size_t bytes) -> void* {
        void* p = ws + off;
        off = (off + bytes + 255) & ~(size_t)255;
        return p;
    };
    int*      offs   = (int*)carve((size_t)(n + 1) * 4);
    int*      cursor = (int*)carve((size_t)n * 4);
    int*      bsums  = (int*)carve(256 * 4);
    int2*     edges  = (int2*)carve((size_t)E * 8);
    float*    h      = (float*)carve((size_t)n * 96 * 4);   // activations (h / h5 ld64)
    float*    sbuf   = (float*)carve((size_t)n * 128 * 4);  // s buffers / MLP a1
    float*    Wf     = (float*)carve(96 * 96 * 4);
    float*    stats  = (float*)carve(192 * 4);
    float*    cb     = (float*)carve(96 * 4);
    float*    m      = (float*)carve((size_t)n * 4);
    unsigned* gmin   = (unsigned*)carve(4);
    float*    thresh = (float*)carve(4);
    float* bsum   = stats;
    float* bsumsq = stats + 96;

    hipMemsetAsync(cursor, 0, (size_t)n * 4, stream);
    hipMemsetAsync(stats, 0, 192 * 4, stream);
    hipMemsetAsync(gmin, 0xFF, 4, stream);

    // CSR build
    const int nb = (n + 255) / 256;
    hist_kernel<<<512, 256, 0, stream>>>(row, cursor, E);
    scan1_kernel<<<nb, 256, 0, stream>>>(cursor, offs, bsums, n);
    scan2_kernel<<<1, 256, 0, stream>>>(bsums, nb);
    scan3_kernel<<<nb, 256, 0, stream>>>(offs, cursor, bsums, n, E);
    scatter_kernel<<<512, 256, 0, stream>>>(row, col, val, cursor, edges, E);

    const int gR = (n + 63) / 64;       // 782 row tiles
    const int ga = 2048;                // agg blocks (grid-stride)

    // L1: s = x[:, :128] @ W1 (no cb); h1 = relu(agg(s) + b1), BN stats
    gemmC<128, 48, false, false, false><<<dim3(gR, 2), 256, 0, stream>>>(
        x, XLD, 128, x, XLD, W1, 96, nullptr, nullptr, sbuf, 96, n);
    aggE<3, true><<<ga, 256, 0, stream>>>(sbuf, offs, edges, b1, h, bsum, bsumsq, n);

    // L2: fold; s = h@Wf + cb; h = relu(agg(s) + b2), stats
    fold_kernel<96><<<1, 256, 0, stream>>>(W2, bsum, bsumsq, Wf, cb, n);
    gemmC<96, 48, false, false, true><<<dim3(gR, 2), 256, 0, stream>>>(
        h, 96, 96, h, 96, Wf, 96, nullptr, cb, sbuf, 96, n);
    aggE<3, true><<<ga, 256, 0, stream>>>(sbuf, offs, edges, b2, h, bsum, bsumsq, n);

    // L3
    fold_kernel<96><<<1, 256, 0, stream>>>(W3, bsum, bsumsq, Wf, cb, n);
    gemmC<96, 48, false, false, true><<<dim3(gR, 2), 256, 0, stream>>>(
        h, 96, 96, h, 96, Wf, 96, nullptr, cb, sbuf, 96, n);
    aggE<3, true><<<ga, 256, 0, stream>>>(sbuf, offs, edges, b3, h, bsum, bsumsq, n);

    // L4
    fold_kernel<96><<<1, 256, 0, stream>>>(W4, bsum, bsumsq, Wf, cb, n);
    gemmC<96, 48, false, false, true><<<dim3(gR, 2), 256, 0, stream>>>(
        h, 96, 96, h, 96, Wf, 96, nullptr, cb, sbuf, 96, n);
    aggE<3, true><<<ga, 256, 0, stream>>>(sbuf, offs, edges, b4, h, bsum, bsumsq, n);

    // L5: fold64; s64 = h@Wf5 + cb; h5 = relu(agg(s64) + b5) (64-wide, no stats)
    fold_kernel<64><<<1, 256, 0, stream>>>(W5, bsum, bsumsq, Wf, cb, n);
    gemmC<96, 32, false, false, true><<<dim3(gR, 2), 256, 0, stream>>>(
        h, 96, 96, h, 96, Wf, 64, nullptr, cb, sbuf, 64, n);
    aggE<2, false><<<ga, 256, 0, stream>>>(sbuf, offs, edges, b5, h, bsum, bsumsq, n);

    // MLP: a1 = relu([h5 | x[:,128:160]] @ M1w + M1b) -> sbuf (n x 128)
    gemmC<96, 64, true, true, false><<<dim3(gR, 2), 256, 0, stream>>>(
        h, 64, 64, x + 128, XLD, M1w, 128, M1b, nullptr, sbuf, 128, n);
    // a2 = relu(a1 @ M2w + M2b) -> h (n x 64)
    gemmC<128, 32, true, true, false><<<dim3(gR, 2), 256, 0, stream>>>(
        sbuf, 128, 128, sbuf, 128, M2w, 64, M2b, nullptr, h, 64, n);

    // m = a2 @ M3w + M3b ; global min
    dot_min_kernel<<<256, 256, 0, stream>>>(h, M3w, M3b, m, gmin, n);

    // where(grp==0, min, m)
    where_kernel<<<(n + 255) / 256, 256, 0, stream>>>(x, m, gmin, n);

    // exact 71st-largest threshold
    select_kernel<<<1, 1024, 0, stream>>>(m, n, 71, thresh);

    // out = m>thresh ? m*(1/m) : 0
    mask_kernel<<<(n + 255) / 256, 256, 0, stream>>>(m, thresh, (float*)d_out, n);
}